// Round 1
// 492.093 us; speedup vs baseline: 1.0327x; 1.0327x over previous
//
#include <hip/hip_runtime.h>
#include <math.h>

#define HWD 262144   // 64*64*64
#define C_CH 128
#define B_N 2
#define VT 128       // voxels per k3 tile

typedef float f4 __attribute__((ext_vector_type(4)));

__device__ __forceinline__ float sigmoidf_(float v) {
    return 1.0f / (1.0f + expf(-v));
}

// Cox-de Boor B-spline bases, k=3, GRID_SIZE=5, grid range [-1,1].
// Produces 8 basis values, faithful to the reference (incl. out-of-range -> 0).
__device__ __forceinline__ void bspline8(float x, float* bs) {
    float g[12];
#pragma unroll
    for (int i = 0; i < 12; ++i) g[i] = (float)(i - 3) * 0.4f - 1.0f;
    float b[11];
#pragma unroll
    for (int t = 0; t < 11; ++t) b[t] = (x >= g[t] && x < g[t + 1]) ? 1.0f : 0.0f;
#pragma unroll
    for (int j = 1; j <= 3; ++j) {
#pragma unroll
        for (int t = 0; t + j < 11; ++t) {
            b[t] = (x - g[t]) / (g[t + j] - g[t]) * b[t]
                 + (g[t + j + 1] - x) / (g[t + j + 1] - g[t + 1]) * b[t + 1];
        }
    }
#pragma unroll
    for (int t = 0; t < 8; ++t) bs[t] = b[t];
}

// ---------------- Kernel 1: per-(b,c) mean + max over 262144 voxels ----------
// One block per (b,c). 1024 threads, 64 float4 each, fixed reduction order.
// NOTE: normal (allocating) loads on purpose — this pass populates the 256 MiB
// Infinity Cache with x so that k3's re-read hits L3.
__global__ __launch_bounds__(1024) void k1_pool(const float* __restrict__ x,
                                                float* __restrict__ ws) {
    int bid = blockIdx.x;                 // b*128 + c
    const float4* xp = (const float4*)(x + (size_t)bid * HWD);
    int tid = threadIdx.x;
    float s = 0.0f, m = -INFINITY;
#pragma unroll 4
    for (int i = 0; i < 64; ++i) {
        float4 v = xp[(size_t)i * 1024 + tid];
        s += (v.x + v.y) + (v.z + v.w);
        m = fmaxf(m, fmaxf(fmaxf(v.x, v.y), fmaxf(v.z, v.w)));
    }
#pragma unroll
    for (int off = 32; off > 0; off >>= 1) {
        s += __shfl_xor(s, off, 64);
        m = fmaxf(m, __shfl_xor(m, off, 64));
    }
    __shared__ float ssum[16], smax[16];
    int wave = tid >> 6, lane = tid & 63;
    if (lane == 0) { ssum[wave] = s; smax[wave] = m; }
    __syncthreads();
    if (tid == 0) {
        float S = 0.0f, M = -INFINITY;
#pragma unroll
        for (int w = 0; w < 16; ++w) { S += ssum[w]; M = fmaxf(M, smax[w]); }
        ws[bid]       = S / (float)HWD;   // y_avg
        ws[256 + bid] = M;                // y_max
    }
}

// ---------------- Kernel 2: channel attention (tiny KAN MLP) -----------------
// ws layout (floats): [0,256) y_avg, [256,512) y_max, [512,768) catt,
// [768,1024) w2 = catt * conv_w.
__global__ __launch_bounds__(512) void k2_catt(const float* ws_in,
                                               const float* __restrict__ ck1_base,
                                               const float* __restrict__ ck1_spline,
                                               const float* __restrict__ ck2_base,
                                               const float* __restrict__ ck2_spline,
                                               const float* __restrict__ conv_w,
                                               float* ws_out) {
    __shared__ float part[512 * 8];     // per-thread layer-1 partials
    __shared__ float h1silu[32];
    __shared__ float h1bs[32][8];
    __shared__ float out2[512];
    int t = threadIdx.x;
    // Phase A: layer-1 contributions. t = ysel*256 + b*128 + i
    {
        int ysel = t >> 8, b = (t >> 7) & 1, i = t & 127;
        float v = ws_in[ysel * 256 + b * 128 + i];
        float sv = v * sigmoidf_(v);     // silu
        float bs[8];
        bspline8(v, bs);
#pragma unroll
        for (int r = 0; r < 8; ++r) {
            float acc = sv * ck1_base[r * 128 + i];
#pragma unroll
            for (int g = 0; g < 8; ++g)
                acc += bs[g] * ck1_spline[(r * 128 + i) * 8 + g];
            part[t * 8 + r] = acc;
        }
    }
    __syncthreads();
    // Deterministic reduce over i, then relu + silu/spline of h1.
    if (t < 32) {                        // t = ysel*16 + b*8 + r
        int ysel = t >> 4, b = (t >> 3) & 1, r = t & 7;
        int tb = ysel * 256 + b * 128;
        float acc = 0.0f;
        for (int i = 0; i < 128; ++i) acc += part[(tb + i) * 8 + r];
        float h = fmaxf(acc, 0.0f);      // relu
        h1silu[t] = h * sigmoidf_(h);
        bspline8(h, h1bs[t]);
    }
    __syncthreads();
    // Phase B: layer-2. t = ysel*256 + b*128 + o
    {
        int ysel = t >> 8, b = (t >> 7) & 1, o = t & 127;
        float acc = 0.0f;
#pragma unroll
        for (int r = 0; r < 8; ++r) {
            int hidx = ysel * 16 + b * 8 + r;
            acc += h1silu[hidx] * ck2_base[o * 8 + r];
#pragma unroll
            for (int g = 0; g < 8; ++g)
                acc += h1bs[hidx][g] * ck2_spline[(o * 8 + r) * 8 + g];
        }
        out2[t] = acc;
    }
    __syncthreads();
    if (t < 256) {                       // t = b*128 + o
        int o = t & 127;
        float catt = sigmoidf_(out2[t] + out2[256 + t]);   // avg-path + max-path
        ws_out[512 + t] = catt;
        ws_out[768 + t] = catt * conv_w[o];
    }
}

// ---------------- Kernel 3: main fused pass ---------------------------------
// Block handles VT=128 consecutive voxels for one b across all 128 channels.
// x tile staged in LDS -> x read exactly once here, as L3 hits (k1 populated
// the Infinity Cache; our stores are non-temporal so they don't evict x).
__global__ __launch_bounds__(512) void k3_main(const float* __restrict__ x,
                                               const float* __restrict__ ws,
                                               const float* __restrict__ sk_base,
                                               const float* __restrict__ sk_spline,
                                               float* __restrict__ out) {
    __shared__ __align__(16) float xs[C_CH * VT];   // 64 KB
    __shared__ float partial[512];
    __shared__ __align__(16) float satt[VT];
    __shared__ float catts[C_CH];
    __shared__ float w2s[C_CH];
    int tid = threadIdx.x;
    int bid = blockIdx.x;
    int b = bid >> 11;                   // 2048 chunks per batch (262144/128)
    int v0 = (bid & 2047) << 7;
    if (tid < 128) {
        catts[tid] = ws[512 + b * 128 + tid];
        w2s[tid]   = ws[768 + b * 128 + tid];
    }
    const float* xb = x + (size_t)b * C_CH * HWD + v0;
    // Load 128x128 tile: 4096 float4, 8 per thread. 32 float4 per channel-row.
    // Non-temporal: each x line is consumed exactly once here; don't re-allocate.
#pragma unroll
    for (int m = 0; m < 8; ++m) {
        int f = m * 512 + tid;
        int c = f >> 5;
        int j = f & 31;
        f4 v = __builtin_nontemporal_load((const f4*)(xb + (size_t)c * HWD + j * 4));
        *(f4*)&xs[c * VT + j * 4] = v;
    }
    __syncthreads();
    // s[v] = sum_c xs[c][v] * w2[c]; 4 partial sums per voxel.
    {
        int v = tid & (VT - 1), q = tid >> 7;
        float acc = 0.0f;
#pragma unroll
        for (int cc = 0; cc < 32; ++cc) {
            int c = q * 32 + cc;
            acc += xs[c * VT + v] * w2s[c];
        }
        partial[tid] = acc;
    }
    __syncthreads();
    if (tid < VT) {
        float s = partial[tid] + partial[tid + 128] + partial[tid + 256] + partial[tid + 384];
        float bs[8];
        bspline8(s, bs);
        float a = s * sigmoidf_(s) * sk_base[0];
#pragma unroll
        for (int g = 0; g < 8; ++g) a += bs[g] * sk_spline[g];
        satt[tid] = sigmoidf_(a);
    }
    __syncthreads();
    float* ob = out + (size_t)b * C_CH * HWD + v0;
#pragma unroll
    for (int m = 0; m < 8; ++m) {
        int f = m * 512 + tid;
        int c = f >> 5;
        int j = f & 31;
        f4 v = *(f4*)&xs[c * VT + j * 4];
        f4 sa = *(f4*)&satt[j * 4];
        float ca = catts[c];
        f4 o = v * ca * sa;
        // Non-temporal store: out is never re-read; don't evict x from L3.
        __builtin_nontemporal_store(o, (f4*)(ob + (size_t)c * HWD + j * 4));
    }
}

extern "C" void kernel_launch(void* const* d_in, const int* in_sizes, int n_in,
                              void* d_out, int out_size, void* d_ws, size_t ws_size,
                              hipStream_t stream) {
    const float* x          = (const float*)d_in[0];
    const float* ck1_base   = (const float*)d_in[1];
    const float* ck1_spline = (const float*)d_in[2];
    const float* ck2_base   = (const float*)d_in[3];
    const float* ck2_spline = (const float*)d_in[4];
    const float* conv_w     = (const float*)d_in[5];
    const float* sk_base    = (const float*)d_in[6];
    const float* sk_spline  = (const float*)d_in[7];
    float* out = (float*)d_out;
    float* ws  = (float*)d_ws;

    k1_pool<<<B_N * C_CH, 1024, 0, stream>>>(x, ws);
    k2_catt<<<1, 512, 0, stream>>>(ws, ck1_base, ck1_spline, ck2_base, ck2_spline,
                                   conv_w, ws);
    k3_main<<<B_N * (HWD / VT), 512, 0, stream>>>(x, ws, sk_base, sk_spline, out);
}